// Round 1
// baseline (189.461 us; speedup 1.0000x reference)
//
#include <hip/hip_runtime.h>
#include <hip/hip_bf16.h>
#include <stdint.h>

#define B 16
#define N 32
#define C 512
#define FEAT 224

// ---------------- Kernel A: conf map -> sigmoid -> avgpool8 ----------------
// grid = B * 16 (16 chunks of 49 cells), block = 64
__global__ __launch_bounds__(64) void att_kernel(const float* __restrict__ confs,
                                                 const float* __restrict__ boxes,
                                                 float* __restrict__ att /* [B][784] */) {
    int b = blockIdx.x >> 4;
    int chunk = blockIdx.x & 15;
    int t = threadIdx.x;

    __shared__ int4 ib[N];
    __shared__ float sconf[N];
    __shared__ uint32_t rm[FEAT], cm[FEAT];

    if (t < N) {
        const float* bb = boxes + (size_t)(b * N + t) * 4;
        int x1 = (int)floorf(bb[0] * 224.f);
        int y1 = (int)floorf(bb[1] * 224.f);
        int x2 = (int)floorf(bb[2] * 224.f);
        int y2 = (int)floorf(bb[3] * 224.f);
        ib[t] = make_int4(x1, y1, x2, y2);
        sconf[t] = confs[b * N + t];
    }
    __syncthreads();

    for (int y = t; y < FEAT; y += 64) {
        uint32_t r = 0, c = 0;
        for (int n = 0; n < N; ++n) {
            int4 v = ib[n];
            if (y >= v.y && y < v.w) r |= (1u << n);
            if (y >= v.x && y < v.z) c |= (1u << n);
        }
        rm[y] = r;
        cm[y] = c;
    }
    __syncthreads();

    if (t < 49) {
        int cell = chunk * 49 + t;       // 0..783
        int cy = cell / 28, cx = cell % 28;
        float sum = 0.f;
        for (int dy = 0; dy < 8; ++dy) {
            uint32_t r = rm[cy * 8 + dy];
            for (int dx = 0; dx < 8; ++dx) {
                uint32_t m = r & cm[cx * 8 + dx];
                float v = 0.f;
                while (m) {
                    int n = __ffs(m) - 1;
                    v += sconf[n];
                    m &= m - 1;
                }
                sum += 1.f / (1.f + __expf(-v));   // sigmoid
            }
        }
        att[b * 784 + cell] = sum * (1.f / 64.f);
    }
}

// ---------------- Kernel B: logits[l][b][c] = sum_hw feat*att -------------
// grid = B*16 (channel group of 32), block = 256 (4 waves, 8 ch per wave)
__global__ __launch_bounds__(256) void logits_kernel(const float* __restrict__ f0,
                                                     const float* __restrict__ f1,
                                                     const float* __restrict__ f2,
                                                     const float* __restrict__ att,
                                                     float* __restrict__ logits /* [3][B][C] */) {
    int b = blockIdx.x >> 4;
    int cg = blockIdx.x & 15;
    int t = threadIdx.x;

    __shared__ float a8[784], a16[196], a32[49];
    const float* ab = att + b * 784;
    for (int i = t; i < 784; i += 256) a8[i] = ab[i];
    __syncthreads();
    if (t < 196) {
        int i = t / 14, j = t % 14;
        a16[t] = 0.25f * (a8[(2 * i) * 28 + 2 * j] + a8[(2 * i) * 28 + 2 * j + 1] +
                          a8[(2 * i + 1) * 28 + 2 * j] + a8[(2 * i + 1) * 28 + 2 * j + 1]);
    }
    __syncthreads();
    if (t < 49) {
        int i = t / 7, j = t % 7;
        a32[t] = 0.25f * (a16[(2 * i) * 14 + 2 * j] + a16[(2 * i) * 14 + 2 * j + 1] +
                          a16[(2 * i + 1) * 14 + 2 * j] + a16[(2 * i + 1) * 14 + 2 * j + 1]);
    }
    __syncthreads();

    int wave = t >> 6, lane = t & 63;
    for (int cc = 0; cc < 8; ++cc) {
        int c = cg * 32 + wave * 8 + cc;
        const float* p0 = f0 + (size_t)(b * C + c) * 784;
        const float* p1 = f1 + (size_t)(b * C + c) * 196;
        const float* p2 = f2 + (size_t)(b * C + c) * 49;
        float s0 = 0.f, s1 = 0.f, s2 = 0.f;
        for (int i = lane; i < 784; i += 64) s0 += p0[i] * a8[i];
        for (int i = lane; i < 196; i += 64) s1 += p1[i] * a16[i];
        if (lane < 49) s2 = p2[lane] * a32[lane];
        for (int o = 32; o; o >>= 1) {
            s0 += __shfl_down(s0, o);
            s1 += __shfl_down(s1, o);
            s2 += __shfl_down(s2, o);
        }
        if (lane == 0) {
            int idx = b * C + c;
            logits[idx] = s0;
            logits[B * C + idx] = s1;
            logits[2 * B * C + idx] = s2;
        }
    }
}

// ---------------- Kernel Bs: softmax over C per (level,b) -----------------
// grid = 48, block = 64
__global__ __launch_bounds__(64) void softmax_kernel(const float* __restrict__ logits,
                                                     float* __restrict__ w) {
    int row = blockIdx.x;      // level*B + b
    int lane = threadIdx.x;
    const float* lp = logits + row * C;
    float v[8];
    float mx = -1e30f;
    for (int k = 0; k < 8; ++k) {
        v[k] = lp[lane + 64 * k];
        mx = fmaxf(mx, v[k]);
    }
    for (int o = 32; o; o >>= 1) mx = fmaxf(mx, __shfl_xor(mx, o));
    float s = 0.f;
    for (int k = 0; k < 8; ++k) {
        v[k] = __expf(v[k] - mx);
        s += v[k];
    }
    for (int o = 32; o; o >>= 1) s += __shfl_xor(s, o);
    float inv = 1.f / s;
    float* wp = w + row * C;
    for (int k = 0; k < 8; ++k) wp[lane + 64 * k] = v[k] * inv;
}

// ---------------- Kernel C: out = feat * w, concat layout -----------------
#define L0V (B * C * 196)            // 1605632 float4s
#define L1V (B * C * 49)             // 401408
#define L2V (B * 6272)               // 100352
#define TOTV (L0V + L1V + L2V)       // 2107392
#define SLAB4 131712                 // 526848/4 per-batch out float4s

__global__ __launch_bounds__(256) void scale_kernel(const float4* __restrict__ f0,
                                                    const float4* __restrict__ f1,
                                                    const float4* __restrict__ f2,
                                                    const float* __restrict__ w /* [3][B][C] */,
                                                    float4* __restrict__ out) {
    int stride = gridDim.x * 256;
    for (int v = blockIdx.x * 256 + threadIdx.x; v < TOTV; v += stride) {
        if (v < L0V) {
            int b = v / 100352;
            int r = v - b * 100352;          // c*196 + h4
            int c = r / 196;
            float s = w[b * C + c];
            float4 x = f0[v];
            float4 y = make_float4(x.x * s, x.y * s, x.z * s, x.w * s);
            out[b * SLAB4 + r] = y;
        } else if (v < L0V + L1V) {
            int u = v - L0V;
            int b = u / 25088;
            int r = u - b * 25088;           // c*49 + h4
            int c = r / 49;
            float s = w[B * C + b * C + c];
            float4 x = f1[u];
            float4 y = make_float4(x.x * s, x.y * s, x.z * s, x.w * s);
            out[b * SLAB4 + 100352 + r] = y;
        } else {
            int u = v - L0V - L1V;
            int b = u / 6272;
            int r = u - b * 6272;            // vec4 within slab (49 floats/channel)
            float4 x = f2[u];
            uint32_t idx = (uint32_t)r * 4u;
            // exact floor(idx/49) for idx < 25088: (idx*85599)>>22
            uint32_t c0 = (idx * 85599u) >> 22;
            uint32_t c1 = ((idx + 1u) * 85599u) >> 22;
            uint32_t c2 = ((idx + 2u) * 85599u) >> 22;
            uint32_t c3 = ((idx + 3u) * 85599u) >> 22;
            const float* w2 = w + 2 * B * C + b * C;
            float4 y = make_float4(x.x * w2[c0], x.y * w2[c1], x.z * w2[c2], x.w * w2[c3]);
            out[b * SLAB4 + 125440 + r] = y;
        }
    }
}

// --------------------------------------------------------------------------
extern "C" void kernel_launch(void* const* d_in, const int* in_sizes, int n_in,
                              void* d_out, int out_size, void* d_ws, size_t ws_size,
                              hipStream_t stream) {
    const float* confs = (const float*)d_in[0];   // [16][32]
    const float* boxes = (const float*)d_in[1];   // [16][32][4]
    const float* f0 = (const float*)d_in[2];      // [16][512][28][28]
    const float* f1 = (const float*)d_in[3];      // [16][512][14][14]
    const float* f2 = (const float*)d_in[4];      // [16][512][7][7]
    float* out = (float*)d_out;

    float* ws = (float*)d_ws;
    float* att = ws;                       // 16*784            = 12544
    float* logits = ws + 12544;            // 3*16*512          = 24576
    float* w = ws + 12544 + 24576;         // 3*16*512          = 24576

    att_kernel<<<B * 16, 64, 0, stream>>>(confs, boxes, att);
    logits_kernel<<<B * 16, 256, 0, stream>>>(f0, f1, f2, att, logits);
    softmax_kernel<<<48, 64, 0, stream>>>(logits, w);
    scale_kernel<<<2048, 256, 0, stream>>>((const float4*)f0, (const float4*)f1,
                                           (const float4*)f2, w, (float4*)out);
}

// Round 2
// 134.913 us; speedup vs baseline: 1.4043x; 1.4043x over previous
//
#include <hip/hip_runtime.h>
#include <hip/hip_bf16.h>
#include <stdint.h>

#define B 16
#define N 32
#define C 512
#define FEAT 224

// ---------------- Kernel A: conf map -> sigmoid -> avgpool8 ----------------
// grid = B * 16 (16 chunks of 49 cells), block = 64
__global__ __launch_bounds__(64) void att_kernel(const float* __restrict__ confs,
                                                 const float* __restrict__ boxes,
                                                 float* __restrict__ att /* [B][784] */) {
    int b = blockIdx.x >> 4;
    int chunk = blockIdx.x & 15;
    int t = threadIdx.x;

    __shared__ int4 ib[N];
    __shared__ float sconf[N];
    __shared__ uint32_t rm[FEAT], cm[FEAT];

    if (t < N) {
        const float* bb = boxes + (size_t)(b * N + t) * 4;
        int x1 = (int)floorf(bb[0] * 224.f);
        int y1 = (int)floorf(bb[1] * 224.f);
        int x2 = (int)floorf(bb[2] * 224.f);
        int y2 = (int)floorf(bb[3] * 224.f);
        ib[t] = make_int4(x1, y1, x2, y2);
        sconf[t] = confs[b * N + t];
    }
    __syncthreads();

    for (int y = t; y < FEAT; y += 64) {
        uint32_t r = 0, c = 0;
        for (int n = 0; n < N; ++n) {
            int4 v = ib[n];
            if (y >= v.y && y < v.w) r |= (1u << n);
            if (y >= v.x && y < v.z) c |= (1u << n);
        }
        rm[y] = r;
        cm[y] = c;
    }
    __syncthreads();

    if (t < 49) {
        int cell = chunk * 49 + t;       // 0..783
        int cy = cell / 28, cx = cell % 28;
        float sum = 0.f;
        for (int dy = 0; dy < 8; ++dy) {
            uint32_t r = rm[cy * 8 + dy];
            for (int dx = 0; dx < 8; ++dx) {
                uint32_t m = r & cm[cx * 8 + dx];
                float v = 0.f;
                while (m) {
                    int n = __ffs(m) - 1;
                    v += sconf[n];
                    m &= m - 1;
                }
                sum += 1.f / (1.f + __expf(-v));   // sigmoid
            }
        }
        att[b * 784 + cell] = sum * (1.f / 64.f);
    }
}

// ---------------- Kernel B: logits[l][b][c] = sum_hw feat*att -------------
// grid = B * C/4 = 2048 blocks, block = 256 (4 waves), one wave per channel
__global__ __launch_bounds__(256) void logits_kernel(const float* __restrict__ f0,
                                                     const float* __restrict__ f1,
                                                     const float* __restrict__ f2,
                                                     const float* __restrict__ att,
                                                     float* __restrict__ logits /* [3][B][C] */) {
    int b = blockIdx.x >> 7;          // / 128
    int cg = blockIdx.x & 127;        // channel group of 4
    int t = threadIdx.x;

    __shared__ __align__(16) float a8[784];
    __shared__ float a16[196], a32[49];

    // stage att[b] as float4 (784 floats = 196 float4, base 16B-aligned)
    {
        const float4* abv = (const float4*)(att + b * 784);
        float4* a8v = (float4*)a8;
        if (t < 196) a8v[t] = abv[t];
    }
    __syncthreads();
    if (t < 196) {
        int i = t / 14, j = t % 14;
        a16[t] = 0.25f * (a8[(2 * i) * 28 + 2 * j] + a8[(2 * i) * 28 + 2 * j + 1] +
                          a8[(2 * i + 1) * 28 + 2 * j] + a8[(2 * i + 1) * 28 + 2 * j + 1]);
    }
    __syncthreads();
    if (t < 49) {
        int i = t / 7, j = t % 7;
        a32[t] = 0.25f * (a16[(2 * i) * 14 + 2 * j] + a16[(2 * i) * 14 + 2 * j + 1] +
                          a16[(2 * i + 1) * 14 + 2 * j] + a16[(2 * i + 1) * 14 + 2 * j + 1]);
    }
    __syncthreads();

    int wave = t >> 6, lane = t & 63;
    int c = cg * 4 + wave;

    const float4* p0 = (const float4*)(f0 + (size_t)(b * C + c) * 784); // 196 float4
    const float4* p1 = (const float4*)(f1 + (size_t)(b * C + c) * 196); // 49 float4
    const float*  p2 = f2 + (size_t)(b * C + c) * 49;                   // 49 floats
    const float4* a8v = (const float4*)a8;
    const float4* a16v = (const float4*)a16;  // a16 is 4-float aligned? ensure below

    // issue all loads up front for ILP
    float4 x0 = p0[lane];
    float4 x1 = p0[lane + 64];
    float4 x2 = p0[lane + 128];
    float4 x3 = (lane < 4) ? p0[lane + 192] : make_float4(0.f, 0.f, 0.f, 0.f);
    float4 y0 = (lane < 49) ? p1[lane] : make_float4(0.f, 0.f, 0.f, 0.f);
    float  z0 = (lane < 49) ? p2[lane] : 0.f;

    float4 b0 = a8v[lane];
    float4 b1 = a8v[lane + 64];
    float4 b2 = a8v[lane + 128];
    float4 b3 = (lane < 4) ? a8v[lane + 192] : make_float4(0.f, 0.f, 0.f, 0.f);

    float s0 = x0.x * b0.x + x0.y * b0.y + x0.z * b0.z + x0.w * b0.w;
    s0 += x1.x * b1.x + x1.y * b1.y + x1.z * b1.z + x1.w * b1.w;
    s0 += x2.x * b2.x + x2.y * b2.y + x2.z * b2.z + x2.w * b2.w;
    s0 += x3.x * b3.x + x3.y * b3.y + x3.z * b3.z + x3.w * b3.w;

    float s1 = 0.f, s2 = 0.f;
    if (lane < 49) {
        float4 c1 = a16v[lane];
        s1 = y0.x * c1.x + y0.y * c1.y + y0.z * c1.z + y0.w * c1.w;
        s2 = z0 * a32[lane];
    }

    for (int o = 32; o; o >>= 1) {
        s0 += __shfl_down(s0, o);
        s1 += __shfl_down(s1, o);
        s2 += __shfl_down(s2, o);
    }
    if (lane == 0) {
        int idx = b * C + c;
        logits[idx] = s0;
        logits[B * C + idx] = s1;
        logits[2 * B * C + idx] = s2;
    }
}

// ---------------- Kernel Bs: softmax over C per (level,b) -----------------
// grid = 48, block = 64
__global__ __launch_bounds__(64) void softmax_kernel(const float* __restrict__ logits,
                                                     float* __restrict__ w) {
    int row = blockIdx.x;      // level*B + b
    int lane = threadIdx.x;
    const float* lp = logits + row * C;
    float v[8];
    float mx = -1e30f;
    for (int k = 0; k < 8; ++k) {
        v[k] = lp[lane + 64 * k];
        mx = fmaxf(mx, v[k]);
    }
    for (int o = 32; o; o >>= 1) mx = fmaxf(mx, __shfl_xor(mx, o));
    float s = 0.f;
    for (int k = 0; k < 8; ++k) {
        v[k] = __expf(v[k] - mx);
        s += v[k];
    }
    for (int o = 32; o; o >>= 1) s += __shfl_xor(s, o);
    float inv = 1.f / s;
    float* wp = w + row * C;
    for (int k = 0; k < 8; ++k) wp[lane + 64 * k] = v[k] * inv;
}

// ---------------- Kernel C: out = feat * w, concat layout -----------------
#define L0V (B * C * 196)            // 1605632 float4s
#define L1V (B * C * 49)             // 401408
#define L2V (B * 6272)               // 100352
#define TOTV (L0V + L1V + L2V)       // 2107392
#define SLAB4 131712                 // 526848/4 per-batch out float4s

__global__ __launch_bounds__(256) void scale_kernel(const float4* __restrict__ f0,
                                                    const float4* __restrict__ f1,
                                                    const float4* __restrict__ f2,
                                                    const float* __restrict__ w /* [3][B][C] */,
                                                    float4* __restrict__ out) {
    int stride = gridDim.x * 256;
    for (int v = blockIdx.x * 256 + threadIdx.x; v < TOTV; v += stride) {
        if (v < L0V) {
            int b = v / 100352;
            int r = v - b * 100352;          // c*196 + h4
            int c = r / 196;
            float s = w[b * C + c];
            float4 x = f0[v];
            float4 y = make_float4(x.x * s, x.y * s, x.z * s, x.w * s);
            out[b * SLAB4 + r] = y;
        } else if (v < L0V + L1V) {
            int u = v - L0V;
            int b = u / 25088;
            int r = u - b * 25088;           // c*49 + h4
            int c = r / 49;
            float s = w[B * C + b * C + c];
            float4 x = f1[u];
            float4 y = make_float4(x.x * s, x.y * s, x.z * s, x.w * s);
            out[b * SLAB4 + 100352 + r] = y;
        } else {
            int u = v - L0V - L1V;
            int b = u / 6272;
            int r = u - b * 6272;            // vec4 within slab (49 floats/channel)
            float4 x = f2[u];
            uint32_t idx = (uint32_t)r * 4u;
            // exact floor(idx/49) for idx < 25088: (idx*85599)>>22
            uint32_t c0 = (idx * 85599u) >> 22;
            uint32_t c1 = ((idx + 1u) * 85599u) >> 22;
            uint32_t c2 = ((idx + 2u) * 85599u) >> 22;
            uint32_t c3 = ((idx + 3u) * 85599u) >> 22;
            const float* w2 = w + 2 * B * C + b * C;
            float4 y = make_float4(x.x * w2[c0], x.y * w2[c1], x.z * w2[c2], x.w * w2[c3]);
            out[b * SLAB4 + 125440 + r] = y;
        }
    }
}

// --------------------------------------------------------------------------
extern "C" void kernel_launch(void* const* d_in, const int* in_sizes, int n_in,
                              void* d_out, int out_size, void* d_ws, size_t ws_size,
                              hipStream_t stream) {
    const float* confs = (const float*)d_in[0];   // [16][32]
    const float* boxes = (const float*)d_in[1];   // [16][32][4]
    const float* f0 = (const float*)d_in[2];      // [16][512][28][28]
    const float* f1 = (const float*)d_in[3];      // [16][512][14][14]
    const float* f2 = (const float*)d_in[4];      // [16][512][7][7]
    float* out = (float*)d_out;

    float* ws = (float*)d_ws;
    float* att = ws;                       // 16*784            = 12544
    float* logits = ws + 12544;            // 3*16*512          = 24576
    float* w = ws + 12544 + 24576;         // 3*16*512          = 24576

    att_kernel<<<B * 16, 64, 0, stream>>>(confs, boxes, att);
    logits_kernel<<<B * C / 4, 256, 0, stream>>>(f0, f1, f2, att, logits);
    softmax_kernel<<<48, 64, 0, stream>>>(logits, w);
    scale_kernel<<<2048, 256, 0, stream>>>((const float4*)f0, (const float4*)f1,
                                           (const float4*)f2, w, (float4*)out);
}